// Round 14
// baseline (1545.858 us; speedup 1.0000x reference)
//
#include <hip/hip_runtime.h>
#include <math.h>

#define Bn 128
#define Tn 512
#define Dn 32
#define Hn 128
#define Gn 512   // 4*H
#define Ln 3
#define Sc 8            // timesteps per chunk
#define NC (Tn / Sc)    // 64 chunks

// LDS-only barrier: does NOT drain vmcnt.
#define BAR_LDS() asm volatile("s_waitcnt lgkmcnt(0)\n\ts_barrier" ::: "memory")

typedef _Float16 h2 __attribute__((ext_vector_type(2)));

__device__ __forceinline__ float dot2(h2 a, h2 b, float c) {
    return __builtin_amdgcn_fdot2(a, b, c, false);
}
__device__ __forceinline__ h2 pkh(float a, float b) {
    h2 r; r.x = (_Float16)a; r.y = (_Float16)b; return r;
}
__device__ __forceinline__ h2 bcast2(h2 v, int l) {
    int i = __builtin_amdgcn_readlane(__builtin_bit_cast(int, v), l);
    return __builtin_bit_cast(h2, i);
}
#define BCh(f) __builtin_bit_cast(h2, (f))
__device__ __forceinline__ float sigm(float x) {
    return __builtin_amdgcn_rcpf(1.f + __expf(-x));
}
__device__ __forceinline__ float tanh_fast(float x) {
    return 1.f - 2.f * __builtin_amdgcn_rcpf(1.f + __expf(2.f * x));
}

#define KEEPH(x) asm volatile("" : "+v"(x))
#define KEEP16(P) \
  KEEPH(P##0); KEEPH(P##1); KEEPH(P##2); KEEPH(P##3); KEEPH(P##4); KEEPH(P##5); \
  KEEPH(P##6); KEEPH(P##7); KEEPH(P##8); KEEPH(P##9); KEEPH(P##10); KEEPH(P##11); \
  KEEPH(P##12); KEEPH(P##13); KEEPH(P##14); KEEPH(P##15);

// load 16 h2 (32 halfs) from ptr into named regs P0..P15
#define LOADG16(P, ptr) { const float4* _p = (const float4*)(ptr); \
    float4 _v0=_p[0], _v1=_p[1], _v2=_p[2], _v3=_p[3]; \
    P##0=BCh(_v0.x);  P##1=BCh(_v0.y);  P##2=BCh(_v0.z);  P##3=BCh(_v0.w); \
    P##4=BCh(_v1.x);  P##5=BCh(_v1.y);  P##6=BCh(_v1.z);  P##7=BCh(_v1.w); \
    P##8=BCh(_v2.x);  P##9=BCh(_v2.y);  P##10=BCh(_v2.z); P##11=BCh(_v2.w); \
    P##12=BCh(_v3.x); P##13=BCh(_v3.y); P##14=BCh(_v3.z); P##15=BCh(_v3.w); }

// load 4 h2 (8 halfs) into P0..P3
#define LOADG4(P, ptr) { const float4* _p=(const float4*)(ptr); float4 _v=_p[0]; \
    P##0=BCh(_v.x); P##1=BCh(_v.y); P##2=BCh(_v.z); P##3=BCh(_v.w); }

// GEMM-phase MAC: LDS-broadcast x value into the 4 gate accumulators
#define GDOTI(xx, idx) { h2 _x=(xx); \
    aI=dot2(_x,wi##idx,aI); aF=dot2(_x,wf##idx,aF); \
    aG=dot2(_x,wg##idx,aG); aO=dot2(_x,wo##idx,aO); }

// scan-phase MAC: readlane-broadcast h pair into the 4 gate accumulators
#define DOT4(j) { h2 s = bcast2(hx, j);      \
    aI = dot2(s, wi##j, aI);                 \
    aF = dot2(s, wf##j, aF);                 \
    aG = dot2(s, wg##j, aG);                 \
    aO = dot2(s, wo##j, aO); }

// ---------------------------------------------------------------------------
// fp32 -> fp16 convert (n multiple of 4)
// ---------------------------------------------------------------------------
__global__ __launch_bounds__(256) void cvt_f2h(
    const float* __restrict__ in, _Float16* __restrict__ out, int n)
{
    int base = (blockIdx.x * 256 + threadIdx.x) * 4;
    if (base < n) {
        float4 v = *(const float4*)(in + base);
        *(h2*)(out + base)     = pkh(v.x, v.y);
        *(h2*)(out + base + 2) = pkh(v.z, v.w);
    }
}

// ---------------------------------------------------------------------------
// Persistent 3-layer pipelined LSTM. 384 blocks, LAYER-MAJOR block ids
// (blocks [0,128) = layer 0, [128,256) = layer 1, [256,384) = layer 2), so
// producers are always dispatched before consumers: with full co-residency
// (waves_per_eu(4,4) caps VGPR<=128 -> 2 blocks/CU) the layers pipeline at
// chunk granularity; without it the schedule degrades to sequential, never
// deadlocks. Per chunk (S=8 steps): fused input-GEMM (each thread (u,kq)
// computes its own K-quarter of pre for gates i,f,g,o of unit u, 8 t's,
// held in 32 registers - pre never touches memory), then the v5 scan
// (64 pinned h2 w_hh regs, fdot2, psum LDS reduce, 2 LDS barriers/step).
// Cross-layer handoff: hs16 trajectory + device-scope release/acquire flag.
// ---------------------------------------------------------------------------
__global__ __launch_bounds__(512)
__attribute__((amdgpu_waves_per_eu(4, 4)))
void lstm_pipeline(
    const _Float16* __restrict__ xh,      // [B][T][32]
    const _Float16* __restrict__ w0h,     // [512][32]
    const _Float16* __restrict__ wrh,     // [2][512][128]
    const _Float16* __restrict__ whh16,   // [3][512][128]
    const float* __restrict__ b_ih,       // [3][512]
    const float* __restrict__ b_hh,       // [3][512]
    _Float16* __restrict__ hsA,           // layer0 out [B][T][H]
    _Float16* __restrict__ hsB,           // layer1 out
    _Float16* __restrict__ hsC,           // layer2 out
    unsigned int* __restrict__ flags)     // [2][B], zeroed before launch
{
    const int l    = blockIdx.x >> 7;     // layer (layer-major!)
    const int b    = blockIdx.x & 127;
    const int tid  = threadIdx.x;
    const int lane = tid & 63;
    const int u    = tid & 127;           // hidden unit
    const int kq   = tid >> 7;            // k-quarter, wave-pair-uniform

    __shared__ h2 h2_sh[Hn / 2];                  // h as 64 packed pairs
    __shared__ __align__(16) float4 psum[4][Hn];  // 8 KB
    __shared__ __align__(16) h2 Xs[Sc][64];       // input chunk, 2 KB

    const int Kin = (l == 0) ? Dn : Hn;
    const _Float16* Win = (l == 0) ? w0h : (wrh + (size_t)(l - 1) * Gn * Hn);
    const _Float16* Whh = whh16 + (size_t)l * Gn * Hn;
    const _Float16* prev = (l == 1) ? hsA : hsB;      // unused for l==0
    _Float16* outp = (l == 0) ? hsA : ((l == 1) ? hsB : hsC);
    _Float16* hsb = outp + (size_t)b * Tn * Hn;

    // biases (held by update lanes)
    float bI = 0.f, bF = 0.f, bG = 0.f, bO = 0.f;
    if (tid < Hn) {
        bI = b_ih[l * Gn + u]           + b_hh[l * Gn + u];
        bF = b_ih[l * Gn + Hn + u]      + b_hh[l * Gn + Hn + u];
        bG = b_ih[l * Gn + 2 * Hn + u]  + b_hh[l * Gn + 2 * Hn + u];
        bO = b_ih[l * Gn + 3 * Hn + u]  + b_hh[l * Gn + 3 * Hn + u];
    }

    float cr = 0.f;                       // c state (update lanes)
    if (tid < Hn / 2) h2_sh[tid] = pkh(0.f, 0.f);
    __syncthreads();

    const int hslot = kq * 16 + (lane & 15);

    // 64 named h2 weight regs, reused by both phases (w_ih, then w_hh)
    h2 wi0,wi1,wi2,wi3,wi4,wi5,wi6,wi7,wi8,wi9,wi10,wi11,wi12,wi13,wi14,wi15;
    h2 wf0,wf1,wf2,wf3,wf4,wf5,wf6,wf7,wf8,wf9,wf10,wf11,wf12,wf13,wf14,wf15;
    h2 wg0,wg1,wg2,wg3,wg4,wg5,wg6,wg7,wg8,wg9,wg10,wg11,wg12,wg13,wg14,wg15;
    h2 wo0,wo1,wo2,wo3,wo4,wo5,wo6,wo7,wo8,wo9,wo10,wo11,wo12,wo13,wo14,wo15;

    for (int c = 0; c < NC; c++) {
        const int t0 = c * Sc;

        // ---- wait for producer layer ----
        if (l > 0) {
            if (tid == 0) {
                while (__hip_atomic_load(&flags[(l - 1) * Bn + b],
                                         __ATOMIC_ACQUIRE,
                                         __HIP_MEMORY_SCOPE_AGENT) < (unsigned)(c + 1))
                    __builtin_amdgcn_s_sleep(2);
            }
            __syncthreads();
        }

        // ---- stage input chunk into LDS ----
        if (l == 0) {
            if (tid < 32) {              // 8 rows x 16 h2 = 32 b128
                int r = tid >> 2, p = tid & 3;
                const float4* src = (const float4*)(xh + ((size_t)b * Tn + t0 + r) * Dn);
                *(float4*)&Xs[r][p * 4] = src[p];
            }
        } else {
            if (tid < 128) {             // 8 rows x 64 h2 = 128 b128
                int r = tid >> 4, p = tid & 15;
                const float4* src = (const float4*)(prev + ((size_t)b * Tn + t0 + r) * Hn);
                *(float4*)&Xs[r][p * 4] = src[p];
            }
        }
        __syncthreads();

        // ---- fused GEMM phase: acc[t] = w_ih(K-quarter) . x_t ----
        float4 acc[Sc];
        if (l == 0) {
            LOADG4(wi, Win + (size_t)(0 * Hn + u) * Kin + kq * 8)
            LOADG4(wf, Win + (size_t)(1 * Hn + u) * Kin + kq * 8)
            LOADG4(wg, Win + (size_t)(2 * Hn + u) * Kin + kq * 8)
            LOADG4(wo, Win + (size_t)(3 * Hn + u) * Kin + kq * 8)
            #pragma unroll
            for (int t = 0; t < Sc; t++) {
                float aI = 0.f, aF = 0.f, aG = 0.f, aO = 0.f;
                float4 xv = *(const float4*)&Xs[t][kq * 4];
                GDOTI(BCh(xv.x), 0) GDOTI(BCh(xv.y), 1)
                GDOTI(BCh(xv.z), 2) GDOTI(BCh(xv.w), 3)
                acc[t] = make_float4(aI, aF, aG, aO);
            }
        } else {
            LOADG16(wi, Win + (size_t)(0 * Hn + u) * Kin + kq * 32)
            LOADG16(wf, Win + (size_t)(1 * Hn + u) * Kin + kq * 32)
            LOADG16(wg, Win + (size_t)(2 * Hn + u) * Kin + kq * 32)
            LOADG16(wo, Win + (size_t)(3 * Hn + u) * Kin + kq * 32)
            KEEP16(wi) KEEP16(wf) KEEP16(wg) KEEP16(wo)
            #pragma unroll
            for (int t = 0; t < Sc; t++) {
                float aI = 0.f, aF = 0.f, aG = 0.f, aO = 0.f;
                float4 xv0 = *(const float4*)&Xs[t][kq * 16 + 0];
                GDOTI(BCh(xv0.x), 0)  GDOTI(BCh(xv0.y), 1)
                GDOTI(BCh(xv0.z), 2)  GDOTI(BCh(xv0.w), 3)
                float4 xv1 = *(const float4*)&Xs[t][kq * 16 + 4];
                GDOTI(BCh(xv1.x), 4)  GDOTI(BCh(xv1.y), 5)
                GDOTI(BCh(xv1.z), 6)  GDOTI(BCh(xv1.w), 7)
                float4 xv2 = *(const float4*)&Xs[t][kq * 16 + 8];
                GDOTI(BCh(xv2.x), 8)  GDOTI(BCh(xv2.y), 9)
                GDOTI(BCh(xv2.z), 10) GDOTI(BCh(xv2.w), 11)
                float4 xv3 = *(const float4*)&Xs[t][kq * 16 + 12];
                GDOTI(BCh(xv3.x), 12) GDOTI(BCh(xv3.y), 13)
                GDOTI(BCh(xv3.z), 14) GDOTI(BCh(xv3.w), 15)
                acc[t] = make_float4(aI, aF, aG, aO);
            }
        }

        // ---- reload weight regs with w_hh slice (always K=128) ----
        LOADG16(wi, Whh + (size_t)(0 * Hn + u) * Hn + kq * 32)
        LOADG16(wf, Whh + (size_t)(1 * Hn + u) * Hn + kq * 32)
        LOADG16(wg, Whh + (size_t)(2 * Hn + u) * Hn + kq * 32)
        LOADG16(wo, Whh + (size_t)(3 * Hn + u) * Hn + kq * 32)
        KEEP16(wi) KEEP16(wf) KEEP16(wg) KEEP16(wo)

        // ---- scan phase: 8 sequential steps ----
        #pragma unroll
        for (int t = 0; t < Sc; t++) {
            h2 hx = h2_sh[hslot];
            float aI = acc[t].x, aF = acc[t].y, aG = acc[t].z, aO = acc[t].w;
            DOT4(0)  DOT4(1)  DOT4(2)  DOT4(3)
            DOT4(4)  DOT4(5)  DOT4(6)  DOT4(7)
            DOT4(8)  DOT4(9)  DOT4(10) DOT4(11)
            DOT4(12) DOT4(13) DOT4(14) DOT4(15)
            psum[kq][u] = make_float4(aI, aF, aG, aO);
            BAR_LDS();

            if (tid < Hn) {
                float4 s0 = psum[0][u], s1 = psum[1][u];
                float4 s2 = psum[2][u], s3 = psum[3][u];
                float gi = ((s0.x + s1.x) + (s2.x + s3.x)) + bI;
                float gf = ((s0.y + s1.y) + (s2.y + s3.y)) + bF;
                float gg = ((s0.z + s1.z) + (s2.z + s3.z)) + bG;
                float go = ((s0.w + s1.w) + (s2.w + s3.w)) + bO;
                float iv = sigm(gi);
                float fv = sigm(gf);
                float gv = tanh_fast(gg);
                float ov = sigm(go);
                cr = fv * cr + iv * gv;
                float hnew = ov * tanh_fast(cr);
                _Float16 hh = (_Float16)hnew;
                ((_Float16*)h2_sh)[u] = hh;
                hsb[(size_t)(t0 + t) * Hn + u] = hh;
            }
            BAR_LDS();
        }

        // ---- publish chunk to consumer layer ----
        if (l < 2) {
            __syncthreads();    // real barrier: drains vmcnt -> hs stores done
            if (tid == 0)
                __hip_atomic_store(&flags[l * Bn + b], (unsigned)(c + 1),
                                   __ATOMIC_RELEASE, __HIP_MEMORY_SCOPE_AGENT);
        }
    }
}

// ---------------------------------------------------------------------------
// Attention pooling + MLP head (reads fp16 hs). One block per batch item.
// ---------------------------------------------------------------------------
__global__ __launch_bounds__(256) void head_kernel(
    const _Float16* __restrict__ hs16,
    const float* __restrict__ w_attn, const float* __restrict__ b_attn,
    const float* __restrict__ w1, const float* __restrict__ b1,
    const float* __restrict__ w2, const float* __restrict__ b2,
    float* __restrict__ out)
{
    const int b = blockIdx.x;
    const int tid = threadIdx.x;
    __shared__ h2 wa2[Hn / 2];
    __shared__ __align__(16) float sc[Tn];
    __shared__ __align__(16) float red[256];
    __shared__ __align__(16) float ctx_sh[Hn];
    __shared__ __align__(16) float h1_sh[64];

    if (tid < Hn / 2) wa2[tid] = pkh(w_attn[2 * tid], w_attn[2 * tid + 1]);
    __syncthreads();

    const _Float16* hb = hs16 + (size_t)b * Tn * Hn;

    for (int t = tid; t < Tn; t += 256) {
        const h2* hp = (const h2*)(hb + (size_t)t * Hn);
        float s = 0.f;
        #pragma unroll
        for (int k = 0; k < 64; k++) s = dot2(hp[k], wa2[k], s);
        sc[t] = s + b_attn[0];
    }
    __syncthreads();

    float m = fmaxf(sc[tid], sc[tid + 256]);
    red[tid] = m; __syncthreads();
    for (int s_ = 128; s_ > 0; s_ >>= 1) {
        if (tid < s_) red[tid] = fmaxf(red[tid], red[tid + s_]);
        __syncthreads();
    }
    float mx = red[0];
    __syncthreads();
    float e0 = __expf(sc[tid] - mx), e1 = __expf(sc[tid + 256] - mx);
    sc[tid] = e0; sc[tid + 256] = e1;
    red[tid] = e0 + e1; __syncthreads();
    for (int s_ = 128; s_ > 0; s_ >>= 1) {
        if (tid < s_) red[tid] += red[tid + s_];
        __syncthreads();
    }
    float inv = 1.f / red[0];
    __syncthreads();

    {
        int jj = tid & 127, half = tid >> 7;
        float a = 0.f;
        for (int t = half * 256; t < half * 256 + 256; t++)
            a += sc[t] * (float)hb[(size_t)t * Hn + jj];
        red[tid] = a;
        __syncthreads();
        if (tid < Hn) ctx_sh[tid] = (red[tid] + red[tid + Hn]) * inv;
        __syncthreads();
    }

    if (tid < 64) {
        const float4* wvv = (const float4*)(w1 + (size_t)tid * Hn);
        const float4* cv = (const float4*)ctx_sh;
        float s = 0.f;
        #pragma unroll
        for (int k = 0; k < 32; k++) {
            float4 a = wvv[k], c = cv[k];
            s += a.x * c.x + a.y * c.y + a.z * c.z + a.w * c.w;
        }
        h1_sh[tid] = fmaxf(s + b1[tid], 0.f);
    }
    __syncthreads();

    if (tid < 4) {
        float s = 0.f;
        const float* wvv = w2 + tid * 64;
        #pragma unroll
        for (int k = 0; k < 64; k++) s += wvv[k] * h1_sh[k];
        out[b * 4 + tid] = s + b2[tid];
    }
}

// ---------------------------------------------------------------------------
extern "C" void kernel_launch(void* const* d_in, const int* in_sizes, int n_in,
                              void* d_out, int out_size, void* d_ws, size_t ws_size,
                              hipStream_t stream)
{
    const float* x        = (const float*)d_in[0];
    const float* w_ih0    = (const float*)d_in[1];
    const float* w_ih_rest= (const float*)d_in[2];
    const float* w_hh     = (const float*)d_in[3];
    const float* b_ih     = (const float*)d_in[4];
    const float* b_hh     = (const float*)d_in[5];
    const float* w_attn   = (const float*)d_in[6];
    const float* b_attn   = (const float*)d_in[7];
    const float* w1       = (const float*)d_in[8];
    const float* b1       = (const float*)d_in[9];
    const float* w2       = (const float*)d_in[10];
    const float* b2       = (const float*)d_in[11];
    float* out = (float*)d_out;

    const size_t nX  = (size_t)Bn * Tn * Dn;       // 2,097,152
    const size_t nHS = (size_t)Bn * Tn * Hn;       // 8,388,608
    const size_t nW0 = (size_t)Gn * Dn;            // 16,384
    const size_t nWR = (size_t)(Ln - 1) * Gn * Hn; // 131,072
    const size_t nWH = (size_t)Ln * Gn * Hn;       // 196,608

    unsigned int* flags = (unsigned int*)d_ws;     // [2][128], 1 KB region
    _Float16* xh    = (_Float16*)((char*)d_ws + 1024);
    _Float16* w0h   = xh + nX;
    _Float16* wrh   = w0h + nW0;
    _Float16* whh16 = wrh + nWR;
    _Float16* hsA   = whh16 + nWH;
    _Float16* hsB   = hsA + nHS;
    _Float16* hsC   = hsB + nHS;

    // zero the flags (harness re-poisons ws to 0xAA before every launch)
    hipMemsetAsync(flags, 0, 1024, stream);

    // fp32 -> fp16 conversions
    cvt_f2h<<<(int)((nX  / 4 + 255) / 256), 256, 0, stream>>>(x, xh, (int)nX);
    cvt_f2h<<<(int)((nW0 / 4 + 255) / 256), 256, 0, stream>>>(w_ih0, w0h, (int)nW0);
    cvt_f2h<<<(int)((nWR / 4 + 255) / 256), 256, 0, stream>>>(w_ih_rest, wrh, (int)nWR);
    cvt_f2h<<<(int)((nWH / 4 + 255) / 256), 256, 0, stream>>>(w_hh, whh16, (int)nWH);

    // the whole 3-layer pipelined LSTM in one persistent launch
    lstm_pipeline<<<Ln * Bn, 512, 0, stream>>>(
        xh, w0h, wrh, whh16, b_ih, b_hh, hsA, hsB, hsC, flags);

    head_kernel<<<Bn, 256, 0, stream>>>(hsC, w_attn, b_attn, w1, b1, w2, b2, out);
}

// Round 15
// 1479.128 us; speedup vs baseline: 1.0451x; 1.0451x over previous
//
#include <hip/hip_runtime.h>
#include <math.h>

#define Bn 128
#define Tn 512
#define Dn 32
#define Hn 128
#define Gn 512   // 4*H
#define Ln 3
#define Sc 8            // timesteps per chunk
#define NC (Tn / Sc)    // 64 chunks

// LDS-only barrier: does NOT drain vmcnt.
#define BAR_LDS() asm volatile("s_waitcnt lgkmcnt(0)\n\ts_barrier" ::: "memory")

typedef _Float16 h2 __attribute__((ext_vector_type(2)));

__device__ __forceinline__ float dot2(h2 a, h2 b, float c) {
    return __builtin_amdgcn_fdot2(a, b, c, false);
}
__device__ __forceinline__ h2 pkh(float a, float b) {
    h2 r; r.x = (_Float16)a; r.y = (_Float16)b; return r;
}
__device__ __forceinline__ h2 bcast2(h2 v, int l) {
    int i = __builtin_amdgcn_readlane(__builtin_bit_cast(int, v), l);
    return __builtin_bit_cast(h2, i);
}
#define BCh(f) __builtin_bit_cast(h2, (f))
__device__ __forceinline__ float sigm(float x) {
    return __builtin_amdgcn_rcpf(1.f + __expf(-x));
}
__device__ __forceinline__ float tanh_fast(float x) {
    return 1.f - 2.f * __builtin_amdgcn_rcpf(1.f + __expf(2.f * x));
}

#define KEEPH(x) asm volatile("" : "+v"(x))
#define KEEP16(P) \
  KEEPH(P##0); KEEPH(P##1); KEEPH(P##2); KEEPH(P##3); KEEPH(P##4); KEEPH(P##5); \
  KEEPH(P##6); KEEPH(P##7); KEEPH(P##8); KEEPH(P##9); KEEPH(P##10); KEEPH(P##11); \
  KEEPH(P##12); KEEPH(P##13); KEEPH(P##14); KEEPH(P##15);

// load 16 h2 (32 halfs) from ptr into named regs P0..P15
#define LOADG16(P, ptr) { const float4* _p = (const float4*)(ptr); \
    float4 _v0=_p[0], _v1=_p[1], _v2=_p[2], _v3=_p[3]; \
    P##0=BCh(_v0.x);  P##1=BCh(_v0.y);  P##2=BCh(_v0.z);  P##3=BCh(_v0.w); \
    P##4=BCh(_v1.x);  P##5=BCh(_v1.y);  P##6=BCh(_v1.z);  P##7=BCh(_v1.w); \
    P##8=BCh(_v2.x);  P##9=BCh(_v2.y);  P##10=BCh(_v2.z); P##11=BCh(_v2.w); \
    P##12=BCh(_v3.x); P##13=BCh(_v3.y); P##14=BCh(_v3.z); P##15=BCh(_v3.w); }

// load 4 h2 (8 halfs) into P0..P3
#define LOADG4(P, ptr) { const float4* _p=(const float4*)(ptr); float4 _v=_p[0]; \
    P##0=BCh(_v.x); P##1=BCh(_v.y); P##2=BCh(_v.z); P##3=BCh(_v.w); }

// GEMM-phase MAC: LDS-broadcast x value into the 4 gate accumulators
#define GDOTI(xx, idx) { h2 _x=(xx); \
    aI=dot2(_x,wi##idx,aI); aF=dot2(_x,wf##idx,aF); \
    aG=dot2(_x,wg##idx,aG); aO=dot2(_x,wo##idx,aO); }

// scan-phase MAC: readlane-broadcast h pair into the 4 gate accumulators
#define DOT4(j) { h2 s = bcast2(hx, j);      \
    aI = dot2(s, wi##j, aI);                 \
    aF = dot2(s, wf##j, aF);                 \
    aG = dot2(s, wg##j, aG);                 \
    aO = dot2(s, wo##j, aO); }

// ---------------------------------------------------------------------------
// fp32 -> fp16 convert (n multiple of 4)
// ---------------------------------------------------------------------------
__global__ __launch_bounds__(256) void cvt_f2h(
    const float* __restrict__ in, _Float16* __restrict__ out, int n)
{
    int base = (blockIdx.x * 256 + threadIdx.x) * 4;
    if (base < n) {
        float4 v = *(const float4*)(in + base);
        *(h2*)(out + base)     = pkh(v.x, v.y);
        *(h2*)(out + base + 2) = pkh(v.z, v.w);
    }
}

// ---------------------------------------------------------------------------
// Persistent 3-layer pipelined LSTM, v2 (spill-fixed). 384 blocks,
// LAYER-MAJOR ids. Per chunk (Sc=8): fused input-GEMM phase accumulates each
// thread's K-quarter 4-gate partials into LDS preP[t][kq][u] (fp32, 64 KB) --
// NO acc register array (R14's float4 acc[8] + 64 pinned h2 blew the 128-reg
// budget -> total spill, VGPR_Count=64). Scan step t folds back the thread's
// OWN preP value (no extra barrier) and the cross-kq reduce rides the
// existing psum reduce (v5 protocol: kq0 keeps partial in regs, kq1-3 write
// psum). LDS 74.3 KB -> exactly 2 blocks/CU at waves_per_eu(4,4); all 384
// blocks co-resident -> chunk-level layer pipelining (serial depth ~528
// steps vs 1536). Cross-layer handoff: hs16 + device-scope release/acquire
// flags (R14-proven). Layer-major ids + full co-residency => no deadlock.
// ---------------------------------------------------------------------------
__global__ __launch_bounds__(512)
__attribute__((amdgpu_waves_per_eu(4, 4)))
void lstm_pipeline(
    const _Float16* __restrict__ xh,      // [B][T][32]
    const _Float16* __restrict__ w0h,     // [512][32]
    const _Float16* __restrict__ wrh,     // [2][512][128]
    const _Float16* __restrict__ whh16,   // [3][512][128]
    const float* __restrict__ b_ih,       // [3][512]
    const float* __restrict__ b_hh,       // [3][512]
    _Float16* __restrict__ hsA,           // layer0 out [B][T][H]
    _Float16* __restrict__ hsB,           // layer1 out
    _Float16* __restrict__ hsC,           // layer2 out
    unsigned int* __restrict__ flags)     // [2][B], zeroed before launch
{
    const int l    = blockIdx.x >> 7;     // layer (layer-major!)
    const int b    = blockIdx.x & 127;
    const int tid  = threadIdx.x;
    const int lane = tid & 63;
    const int u    = tid & 127;           // hidden unit
    const int kq   = tid >> 7;            // k-quarter, wave-pair-uniform

    __shared__ h2 h2_sh[Hn / 2];                     // 256 B
    __shared__ __align__(16) float4 psum[4][Hn];     // 8 KB
    __shared__ __align__(16) float4 preP[Sc][4][Hn]; // 64 KB  [t][kq][u]
    __shared__ __align__(16) h2 Xs[Sc][64];          // 2 KB

    const int Kin = (l == 0) ? Dn : Hn;
    const _Float16* Win = (l == 0) ? w0h : (wrh + (size_t)(l - 1) * Gn * Hn);
    const _Float16* Whh = whh16 + (size_t)l * Gn * Hn;
    const _Float16* prev = (l == 1) ? hsA : hsB;      // unused for l==0
    _Float16* outp = (l == 0) ? hsA : ((l == 1) ? hsB : hsC);
    _Float16* hsb = outp + (size_t)b * Tn * Hn;

    // biases (held by update lanes)
    float bI = 0.f, bF = 0.f, bG = 0.f, bO = 0.f;
    if (tid < Hn) {
        bI = b_ih[l * Gn + u]           + b_hh[l * Gn + u];
        bF = b_ih[l * Gn + Hn + u]      + b_hh[l * Gn + Hn + u];
        bG = b_ih[l * Gn + 2 * Hn + u]  + b_hh[l * Gn + 2 * Hn + u];
        bO = b_ih[l * Gn + 3 * Hn + u]  + b_hh[l * Gn + 3 * Hn + u];
    }

    float cr = 0.f;                       // c state (update lanes)
    if (tid < Hn / 2) h2_sh[tid] = pkh(0.f, 0.f);
    __syncthreads();

    const int hslot = kq * 16 + (lane & 15);

    // 64 named h2 weight regs, reused: w_ih during GEMM phase, w_hh in scan
    h2 wi0,wi1,wi2,wi3,wi4,wi5,wi6,wi7,wi8,wi9,wi10,wi11,wi12,wi13,wi14,wi15;
    h2 wf0,wf1,wf2,wf3,wf4,wf5,wf6,wf7,wf8,wf9,wf10,wf11,wf12,wf13,wf14,wf15;
    h2 wg0,wg1,wg2,wg3,wg4,wg5,wg6,wg7,wg8,wg9,wg10,wg11,wg12,wg13,wg14,wg15;
    h2 wo0,wo1,wo2,wo3,wo4,wo5,wo6,wo7,wo8,wo9,wo10,wo11,wo12,wo13,wo14,wo15;

    for (int c = 0; c < NC; c++) {
        const int t0 = c * Sc;

        // ---- wait for producer layer ----
        if (l > 0) {
            if (tid == 0) {
                while (__hip_atomic_load(&flags[(l - 1) * Bn + b],
                                         __ATOMIC_ACQUIRE,
                                         __HIP_MEMORY_SCOPE_AGENT) < (unsigned)(c + 1))
                    __builtin_amdgcn_s_sleep(2);
            }
            __syncthreads();
        }

        // ---- stage input chunk into LDS ----
        if (l == 0) {
            if (tid < 32) {              // 8 rows x 4 b128
                int r = tid >> 2, p = tid & 3;
                const float4* src = (const float4*)(xh + ((size_t)b * Tn + t0 + r) * Dn);
                *(float4*)&Xs[r][p * 4] = src[p];
            }
        } else {
            if (tid < 128) {             // 8 rows x 16 b128
                int r = tid >> 4, p = tid & 15;
                const float4* src = (const float4*)(prev + ((size_t)b * Tn + t0 + r) * Hn);
                *(float4*)&Xs[r][p * 4] = src[p];
            }
        }
        __syncthreads();

        // ---- fused GEMM phase: preP[t][kq][u] = w_ih(K-quarter) . x_t ----
        if (l == 0) {
            LOADG4(wi, Win + (size_t)(0 * Hn + u) * Kin + kq * 8)
            LOADG4(wf, Win + (size_t)(1 * Hn + u) * Kin + kq * 8)
            LOADG4(wg, Win + (size_t)(2 * Hn + u) * Kin + kq * 8)
            LOADG4(wo, Win + (size_t)(3 * Hn + u) * Kin + kq * 8)
            #pragma unroll
            for (int t = 0; t < Sc; t++) {
                float aI = 0.f, aF = 0.f, aG = 0.f, aO = 0.f;
                float4 xv = *(const float4*)&Xs[t][kq * 4];
                GDOTI(BCh(xv.x), 0) GDOTI(BCh(xv.y), 1)
                GDOTI(BCh(xv.z), 2) GDOTI(BCh(xv.w), 3)
                preP[t][kq][u] = make_float4(aI, aF, aG, aO);
            }
        } else {
            LOADG16(wi, Win + (size_t)(0 * Hn + u) * Kin + kq * 32)
            LOADG16(wf, Win + (size_t)(1 * Hn + u) * Kin + kq * 32)
            LOADG16(wg, Win + (size_t)(2 * Hn + u) * Kin + kq * 32)
            LOADG16(wo, Win + (size_t)(3 * Hn + u) * Kin + kq * 32)
            KEEP16(wi) KEEP16(wf) KEEP16(wg) KEEP16(wo)
            #pragma unroll
            for (int t = 0; t < Sc; t++) {
                float aI = 0.f, aF = 0.f, aG = 0.f, aO = 0.f;
                float4 xv0 = *(const float4*)&Xs[t][kq * 16 + 0];
                GDOTI(BCh(xv0.x), 0)  GDOTI(BCh(xv0.y), 1)
                GDOTI(BCh(xv0.z), 2)  GDOTI(BCh(xv0.w), 3)
                float4 xv1 = *(const float4*)&Xs[t][kq * 16 + 4];
                GDOTI(BCh(xv1.x), 4)  GDOTI(BCh(xv1.y), 5)
                GDOTI(BCh(xv1.z), 6)  GDOTI(BCh(xv1.w), 7)
                float4 xv2 = *(const float4*)&Xs[t][kq * 16 + 8];
                GDOTI(BCh(xv2.x), 8)  GDOTI(BCh(xv2.y), 9)
                GDOTI(BCh(xv2.z), 10) GDOTI(BCh(xv2.w), 11)
                float4 xv3 = *(const float4*)&Xs[t][kq * 16 + 12];
                GDOTI(BCh(xv3.x), 12) GDOTI(BCh(xv3.y), 13)
                GDOTI(BCh(xv3.z), 14) GDOTI(BCh(xv3.w), 15)
                preP[t][kq][u] = make_float4(aI, aF, aG, aO);
            }
        }

        // ---- reload weight regs with w_hh slice (always K=128) ----
        LOADG16(wi, Whh + (size_t)(0 * Hn + u) * Hn + kq * 32)
        LOADG16(wf, Whh + (size_t)(1 * Hn + u) * Hn + kq * 32)
        LOADG16(wg, Whh + (size_t)(2 * Hn + u) * Hn + kq * 32)
        LOADG16(wo, Whh + (size_t)(3 * Hn + u) * Hn + kq * 32)
        KEEP16(wi) KEEP16(wf) KEEP16(wg) KEEP16(wo)

        // ---- scan phase: Sc sequential steps (v5 protocol) ----
        #pragma unroll
        for (int t = 0; t < Sc; t++) {
            h2 hx = h2_sh[hslot];
            float4 pp = preP[t][kq][u];      // own write -- no barrier needed
            float aI = pp.x, aF = pp.y, aG = pp.z, aO = pp.w;
            DOT4(0)  DOT4(1)  DOT4(2)  DOT4(3)
            DOT4(4)  DOT4(5)  DOT4(6)  DOT4(7)
            DOT4(8)  DOT4(9)  DOT4(10) DOT4(11)
            DOT4(12) DOT4(13) DOT4(14) DOT4(15)
            if (kq != 0) psum[kq][u] = make_float4(aI, aF, aG, aO);
            BAR_LDS();

            if (tid < Hn) {                  // kq==0: reduce + update
                float4 s1 = psum[1][u], s2 = psum[2][u], s3 = psum[3][u];
                float gi = ((aI + s1.x) + (s2.x + s3.x)) + bI;
                float gf = ((aF + s1.y) + (s2.y + s3.y)) + bF;
                float gg = ((aG + s1.z) + (s2.z + s3.z)) + bG;
                float go = ((aO + s1.w) + (s2.w + s3.w)) + bO;
                float iv = sigm(gi);
                float fv = sigm(gf);
                float gv = tanh_fast(gg);
                float ov = sigm(go);
                cr = fv * cr + iv * gv;
                float hnew = ov * tanh_fast(cr);
                _Float16 hh = (_Float16)hnew;
                ((_Float16*)h2_sh)[u] = hh;
                hsb[(size_t)(t0 + t) * Hn + u] = hh;
            }
            BAR_LDS();
        }

        // ---- publish chunk to consumer layer ----
        if (l < 2) {
            __syncthreads();    // drains vmcnt -> hs stores visible
            if (tid == 0)
                __hip_atomic_store(&flags[l * Bn + b], (unsigned)(c + 1),
                                   __ATOMIC_RELEASE, __HIP_MEMORY_SCOPE_AGENT);
        }
    }
}

// ---------------------------------------------------------------------------
// Attention pooling + MLP head (reads fp16 hs). One block per batch item.
// ---------------------------------------------------------------------------
__global__ __launch_bounds__(256) void head_kernel(
    const _Float16* __restrict__ hs16,
    const float* __restrict__ w_attn, const float* __restrict__ b_attn,
    const float* __restrict__ w1, const float* __restrict__ b1,
    const float* __restrict__ w2, const float* __restrict__ b2,
    float* __restrict__ out)
{
    const int b = blockIdx.x;
    const int tid = threadIdx.x;
    __shared__ h2 wa2[Hn / 2];
    __shared__ __align__(16) float sc[Tn];
    __shared__ __align__(16) float red[256];
    __shared__ __align__(16) float ctx_sh[Hn];
    __shared__ __align__(16) float h1_sh[64];

    if (tid < Hn / 2) wa2[tid] = pkh(w_attn[2 * tid], w_attn[2 * tid + 1]);
    __syncthreads();

    const _Float16* hb = hs16 + (size_t)b * Tn * Hn;

    for (int t = tid; t < Tn; t += 256) {
        const h2* hp = (const h2*)(hb + (size_t)t * Hn);
        float s = 0.f;
        #pragma unroll
        for (int k = 0; k < 64; k++) s = dot2(hp[k], wa2[k], s);
        sc[t] = s + b_attn[0];
    }
    __syncthreads();

    float m = fmaxf(sc[tid], sc[tid + 256]);
    red[tid] = m; __syncthreads();
    for (int s_ = 128; s_ > 0; s_ >>= 1) {
        if (tid < s_) red[tid] = fmaxf(red[tid], red[tid + s_]);
        __syncthreads();
    }
    float mx = red[0];
    __syncthreads();
    float e0 = __expf(sc[tid] - mx), e1 = __expf(sc[tid + 256] - mx);
    sc[tid] = e0; sc[tid + 256] = e1;
    red[tid] = e0 + e1; __syncthreads();
    for (int s_ = 128; s_ > 0; s_ >>= 1) {
        if (tid < s_) red[tid] += red[tid + s_];
        __syncthreads();
    }
    float inv = 1.f / red[0];
    __syncthreads();

    {
        int jj = tid & 127, half = tid >> 7;
        float a = 0.f;
        for (int t = half * 256; t < half * 256 + 256; t++)
            a += sc[t] * (float)hb[(size_t)t * Hn + jj];
        red[tid] = a;
        __syncthreads();
        if (tid < Hn) ctx_sh[tid] = (red[tid] + red[tid + Hn]) * inv;
        __syncthreads();
    }

    if (tid < 64) {
        const float4* wvv = (const float4*)(w1 + (size_t)tid * Hn);
        const float4* cv = (const float4*)ctx_sh;
        float s = 0.f;
        #pragma unroll
        for (int k = 0; k < 32; k++) {
            float4 a = wvv[k], c = cv[k];
            s += a.x * c.x + a.y * c.y + a.z * c.z + a.w * c.w;
        }
        h1_sh[tid] = fmaxf(s + b1[tid], 0.f);
    }
    __syncthreads();

    if (tid < 4) {
        float s = 0.f;
        const float* wvv = w2 + tid * 64;
        #pragma unroll
        for (int k = 0; k < 64; k++) s += wvv[k] * h1_sh[k];
        out[b * 4 + tid] = s + b2[tid];
    }
}

// ---------------------------------------------------------------------------
extern "C" void kernel_launch(void* const* d_in, const int* in_sizes, int n_in,
                              void* d_out, int out_size, void* d_ws, size_t ws_size,
                              hipStream_t stream)
{
    const float* x        = (const float*)d_in[0];
    const float* w_ih0    = (const float*)d_in[1];
    const float* w_ih_rest= (const float*)d_in[2];
    const float* w_hh     = (const float*)d_in[3];
    const float* b_ih     = (const float*)d_in[4];
    const float* b_hh     = (const float*)d_in[5];
    const float* w_attn   = (const float*)d_in[6];
    const float* b_attn   = (const float*)d_in[7];
    const float* w1       = (const float*)d_in[8];
    const float* b1       = (const float*)d_in[9];
    const float* w2       = (const float*)d_in[10];
    const float* b2       = (const float*)d_in[11];
    float* out = (float*)d_out;

    const size_t nX  = (size_t)Bn * Tn * Dn;       // 2,097,152
    const size_t nHS = (size_t)Bn * Tn * Hn;       // 8,388,608
    const size_t nW0 = (size_t)Gn * Dn;            // 16,384
    const size_t nWR = (size_t)(Ln - 1) * Gn * Hn; // 131,072
    const size_t nWH = (size_t)Ln * Gn * Hn;       // 196,608

    unsigned int* flags = (unsigned int*)d_ws;     // [2][128], 1 KB region
    _Float16* xh    = (_Float16*)((char*)d_ws + 1024);
    _Float16* w0h   = xh + nX;
    _Float16* wrh   = w0h + nW0;
    _Float16* whh16 = wrh + nWR;
    _Float16* hsA   = whh16 + nWH;
    _Float16* hsB   = hsA + nHS;
    _Float16* hsC   = hsB + nHS;

    // zero the flags (harness re-poisons ws to 0xAA before every launch)
    hipMemsetAsync(flags, 0, 1024, stream);

    // fp32 -> fp16 conversions
    cvt_f2h<<<(int)((nX  / 4 + 255) / 256), 256, 0, stream>>>(x, xh, (int)nX);
    cvt_f2h<<<(int)((nW0 / 4 + 255) / 256), 256, 0, stream>>>(w_ih0, w0h, (int)nW0);
    cvt_f2h<<<(int)((nWR / 4 + 255) / 256), 256, 0, stream>>>(w_ih_rest, wrh, (int)nWR);
    cvt_f2h<<<(int)((nWH / 4 + 255) / 256), 256, 0, stream>>>(w_hh, whh16, (int)nWH);

    // the whole 3-layer pipelined LSTM in one persistent launch
    lstm_pipeline<<<Ln * Bn, 512, 0, stream>>>(
        xh, w0h, wrh, whh16, b_ih, b_hh, hsA, hsB, hsC, flags);

    head_kernel<<<Bn, 256, 0, stream>>>(hsC, w_attn, b_attn, w1, b1, w2, b2, out);
}